// Round 4
// baseline (132.725 us; speedup 1.0000x reference)
//
#include <hip/hip_runtime.h>

// ---------------------------------------------------------------------------
// DistillationLoss, round 4.
// 3 launches: init_ws -> mega (5 pair passes + edge pass, blockIdx.z) -> post.
// R3->R4: JC 256->128 (grid 768->1536 blocks, 6/CU) for latency hiding;
// explicit register double-buffer of the LDS group so ds_read overlaps VALU.
// Pair passes: B chunk staged in LDS as SoA f32x4 (x4,y4,z4,|b|^2 x4);
// TA=8 rows/thread, packed fp32 (v_pk_fma_f32): 2 VALU inst per pair.
// partial min m = |b|^2 - 2 a.b (row |a|^2 added at sqrt stage).
// ---------------------------------------------------------------------------

typedef float f32x2 __attribute__((ext_vector_type(2)));
typedef float f32x4 __attribute__((ext_vector_type(4)));

#define BLK 256
#define TA 8                      // rows per thread -> 2048 rows per block
#define JC 128                    // B points per y-chunk
#define NJG (JC / 4)              // f32x4 groups per chunk

__device__ __forceinline__ float wave_reduce_sum(float v) {
#pragma unroll
  for (int o = 32; o > 0; o >>= 1) v += __shfl_down(v, o, 64);
  return v;
}

// total-order float -> uint (monotone)
__device__ __forceinline__ unsigned flipf(float f) {
  unsigned b = __float_as_uint(f);
  return (b & 0x80000000u) ? ~b : (b | 0x80000000u);
}
__device__ __forceinline__ float unflipf(unsigned u) {
  unsigned b = (u & 0x80000000u) ? (u ^ 0x80000000u) : ~u;
  return __uint_as_float(b);
}

__device__ __forceinline__ f32x2 splat2(float v) {
  f32x2 r; r.x = v; r.y = v; return r;
}

__global__ void init_ws_kernel(unsigned long long* __restrict__ min64, int n64,
                               unsigned* __restrict__ minbits, int nmin,
                               float* __restrict__ zr, int nz) {
  const int stride = gridDim.x * blockDim.x;
  const int t0 = blockIdx.x * blockDim.x + threadIdx.x;
  for (int i = t0; i < n64; i += stride) min64[i] = ~0ull;
  for (int i = t0; i < nmin; i += stride) minbits[i] = 0xFF800000u;  // flip(+inf)
  for (int i = t0; i < nz; i += stride) zr[i] = 0.0f;                // also cnt=0
}

struct Desc {
  const float* A[5];
  const float* B[5];
  void* out[5];          // unsigned* for 0-3, unsigned long long* for 4
  const int* fc; int f;
  const float* sv;
  float* nbr; float* deg; float* acc;
  int nRows, nCols;
};

// Distance body: d = naz*z + nay*y + nax*x + w  (w = |b|^2, na* = -2a)
#define DIST2(d01, d23, X_, Y_, Z_, W_, k)                                 \
  f32x2 d01 = __builtin_elementwise_fma(naz[k], (Z_).xy, (W_).xy);         \
  d01 = __builtin_elementwise_fma(nay[k], (Y_).xy, d01);                   \
  d01 = __builtin_elementwise_fma(nax[k], (X_).xy, d01);                   \
  f32x2 d23 = __builtin_elementwise_fma(naz[k], (Z_).zw, (W_).zw);         \
  d23 = __builtin_elementwise_fma(nay[k], (Y_).zw, d23);                   \
  d23 = __builtin_elementwise_fma(nax[k], (X_).zw, d23);

// blockIdx.z: 0-3 chamfer min passes, 4 argmin pass, 5 edge pass.
__global__ void __launch_bounds__(BLK) mega_kernel(Desc d) {
  const int pass = blockIdx.z;
  const int t = threadIdx.x;

  if (pass == 5) {
    // ---- edge + laplacian accumulation (grid-stride over 3F edges) ----
    const int nE = 3 * d.f;
    const int bid = blockIdx.y * gridDim.x + blockIdx.x;
    const int stride = gridDim.x * gridDim.y * BLK;
    float es = 0.f;
    for (int e = bid * BLK + t; e < nE; e += stride) {
      int a, b;
      if (e < d.f)          { a = d.fc[3 * e + 0];  b = d.fc[3 * e + 1]; }
      else if (e < 2 * d.f) { int q = e - d.f;     a = d.fc[3 * q + 1]; b = d.fc[3 * q + 2]; }
      else                  { int q = e - 2 * d.f; a = d.fc[3 * q + 2]; b = d.fc[3 * q + 0]; }
      float ax = d.sv[3 * a], ay = d.sv[3 * a + 1], az = d.sv[3 * a + 2];
      float bx = d.sv[3 * b], by = d.sv[3 * b + 1], bz = d.sv[3 * b + 2];
      float dx = ax - bx, dy = ay - by, dz = az - bz;
      es += fmaf(dx, dx, fmaf(dy, dy, dz * dz));
      atomicAdd(&d.nbr[3 * a + 0], bx);
      atomicAdd(&d.nbr[3 * a + 1], by);
      atomicAdd(&d.nbr[3 * a + 2], bz);
      atomicAdd(&d.nbr[3 * b + 0], ax);
      atomicAdd(&d.nbr[3 * b + 1], ay);
      atomicAdd(&d.nbr[3 * b + 2], az);
      atomicAdd(&d.deg[a], 1.0f);
      atomicAdd(&d.deg[b], 1.0f);
    }
    es = wave_reduce_sum(es);
    if ((t & 63) == 0) atomicAdd(&d.acc[4], es);
    return;
  }

  // ---- pair pass ----
  __shared__ f32x4 sX[NJG], sY[NJG], sZ[NJG], sW[NJG];
  const float* __restrict__ A = d.A[pass];
  const float* __restrict__ B = d.B[pass];
  const int j0 = blockIdx.y * JC;
  if (t < JC) {
    int j = j0 + t;
    float bx = 0.f, by = 0.f, bz = 0.f, bw = 1e30f;
    if (j < d.nCols) {
      bx = B[3 * j]; by = B[3 * j + 1]; bz = B[3 * j + 2];
      bw = fmaf(bx, bx, fmaf(by, by, bz * bz));
    }
    ((float*)sX)[t] = bx; ((float*)sY)[t] = by;
    ((float*)sZ)[t] = bz; ((float*)sW)[t] = bw;
  }

  const int rowBase = blockIdx.x * (TA * BLK) + t;
  f32x2 nax[TA], nay[TA], naz[TA], m2[TA];
#pragma unroll
  for (int k = 0; k < TA; ++k) {
    int r = rowBase + k * BLK;
    int rc = (r < d.nRows) ? r : 0;
    nax[k] = splat2(-2.0f * A[3 * rc + 0]);
    nay[k] = splat2(-2.0f * A[3 * rc + 1]);
    naz[k] = splat2(-2.0f * A[3 * rc + 2]);
    m2[k] = splat2(1e30f);
  }
  __syncthreads();

  if (pass < 4) {
    f32x4 X = sX[0], Y = sY[0], Z = sZ[0], W = sW[0];
#pragma unroll 2
    for (int jg = 0; jg < NJG - 1; ++jg) {
      f32x4 Xn = sX[jg + 1], Yn = sY[jg + 1], Zn = sZ[jg + 1], Wn = sW[jg + 1];
#pragma unroll
      for (int k = 0; k < TA; ++k) {
        DIST2(d01, d23, X, Y, Z, W, k);
        m2[k] = __builtin_elementwise_min(
            m2[k], __builtin_elementwise_min(d01, d23));
      }
      X = Xn; Y = Yn; Z = Zn; W = Wn;
    }
#pragma unroll
    for (int k = 0; k < TA; ++k) {
      DIST2(d01, d23, X, Y, Z, W, k);
      m2[k] = __builtin_elementwise_min(
          m2[k], __builtin_elementwise_min(d01, d23));
    }
    unsigned* __restrict__ out = (unsigned*)d.out[pass];
#pragma unroll
    for (int k = 0; k < TA; ++k) {
      int r = rowBase + k * BLK;
      if (r < d.nRows) atomicMin(out + r, flipf(fminf(m2[k].x, m2[k].y)));
    }
  } else {
    // argmin pass: track index as float (j < 2^24 exact)
    f32x2 id2[TA];
#pragma unroll
    for (int k = 0; k < TA; ++k) id2[k] = splat2(0.f);
    f32x4 X = sX[0], Y = sY[0], Z = sZ[0], W = sW[0];
    for (int jg = 0; jg < NJG; ++jg) {
      f32x4 Xn, Yn, Zn, Wn;
      if (jg + 1 < NJG) { Xn = sX[jg + 1]; Yn = sY[jg + 1]; Zn = sZ[jg + 1]; Wn = sW[jg + 1]; }
      float jb = (float)(j0 + 4 * jg);
      float j1f = jb + 1.f, j2f = jb + 2.f, j3f = jb + 3.f;
#pragma unroll
      for (int k = 0; k < TA; ++k) {
        DIST2(d01, d23, X, Y, Z, W, k);
        bool c0 = d01.x < m2[k].x;
        m2[k].x = c0 ? d01.x : m2[k].x;  id2[k].x = c0 ? jb  : id2[k].x;
        bool c1 = d01.y < m2[k].y;
        m2[k].y = c1 ? d01.y : m2[k].y;  id2[k].y = c1 ? j1f : id2[k].y;
        bool c2 = d23.x < m2[k].x;
        m2[k].x = c2 ? d23.x : m2[k].x;  id2[k].x = c2 ? j2f : id2[k].x;
        bool c3 = d23.y < m2[k].y;
        m2[k].y = c3 ? d23.y : m2[k].y;  id2[k].y = c3 ? j3f : id2[k].y;
      }
      X = Xn; Y = Yn; Z = Zn; W = Wn;
    }
    unsigned long long* __restrict__ out = (unsigned long long*)d.out[4];
#pragma unroll
    for (int k = 0; k < TA; ++k) {
      int r = rowBase + k * BLK;
      unsigned long long pa =
          ((unsigned long long)flipf(m2[k].x) << 32) | (unsigned)(int)id2[k].x;
      unsigned long long pb =
          ((unsigned long long)flipf(m2[k].y) << 32) | (unsigned)(int)id2[k].y;
      unsigned long long best = pa < pb ? pa : pb;
      if (r < d.nRows) atomicMin(out + r, best);
    }
  }
}

// Fused tail. blockIdx.y: 0 smooth->acc[5], 1 normal->acc[6], 2-5 sqrt-sums
// ->acc[0..3]. Last block (ticket) computes the final scalar.
__global__ void __launch_bounds__(BLK) post_kernel(
    const float* __restrict__ sv, const float* __restrict__ sn,
    const float* __restrict__ tn, const float* __restrict__ tp,
    const float* __restrict__ gp, const float* __restrict__ nbr,
    const float* __restrict__ deg, const unsigned* __restrict__ minbase,
    const unsigned long long* __restrict__ min64,
    int n, int p, int g, int f, float* __restrict__ acc,
    int* __restrict__ cnt, float* __restrict__ out) {
  const int task = blockIdx.y;
  const int i = blockIdx.x * blockDim.x + threadIdx.x;
  float s = 0.f;
  int accIdx;
  if (task == 0) {
    accIdx = 5;
    if (i < n) {
      float dd = fmaxf(deg[i], 1.0f);
      float lx = nbr[3 * i + 0] / dd - sv[3 * i + 0];
      float ly = nbr[3 * i + 1] / dd - sv[3 * i + 1];
      float lz = nbr[3 * i + 2] / dd - sv[3 * i + 2];
      s = sqrtf(fmaf(lx, lx, fmaf(ly, ly, lz * lz)));
    }
  } else if (task == 1) {
    accIdx = 6;
    if (i < n) {
      int idx = (int)(min64[i] & 0xffffffffull);
      float sx = sn[3 * i], sy = sn[3 * i + 1], sz = sn[3 * i + 2];
      float tx = tn[3 * idx], ty = tn[3 * idx + 1], tz = tn[3 * idx + 2];
      float num = fmaf(sx, tx, fmaf(sy, ty, sz * tz));
      float ns = sqrtf(fmaf(sx, sx, fmaf(sy, sy, sz * sz)));
      float nt = sqrtf(fmaf(tx, tx, fmaf(ty, ty, tz * tz)));
      s = num / (fmaxf(ns, 1e-8f) * fmaxf(nt, 1e-8f));
    }
  } else {
    const int seg = task - 2;
    accIdx = seg;
    const float* Aarr = (seg == 1) ? tp : (seg == 3) ? gp : sv;
    const int off = (seg == 0) ? 0 : (seg == 1) ? n : (seg == 2) ? (n + p) : (2 * n + p);
    const int cntN = (seg == 1) ? p : n;
    if (i < cntN) {
      float mval = unflipf(minbase[off + i]);
      float ax = Aarr[3 * i], ay = Aarr[3 * i + 1], az = Aarr[3 * i + 2];
      float aa = fmaf(ax, ax, fmaf(ay, ay, az * az));
      s = sqrtf(fmaxf(mval + aa, 0.0f));
    }
  }
  s = wave_reduce_sum(s);
  if ((threadIdx.x & 63) == 0) atomicAdd(&acc[accIdx], s);

  __syncthreads();
  __threadfence();
  __shared__ int last;
  if (threadIdx.x == 0)
    last = (atomicAdd(cnt, 1) == (int)(gridDim.x * gridDim.y) - 1);
  __syncthreads();
  if (last && threadIdx.x == 0) {
    float a[7];
#pragma unroll
    for (int q = 0; q < 7; ++q) a[q] = atomicAdd(&acc[q], 0.0f);
    float lt = 0.5f * (a[0] / (float)n + a[1] / (float)p);
    float lg = 0.5f * (a[2] / (float)n + a[3] / (float)g);
    float chamfer = 0.7f * lt + 0.3f * lg;
    float edge = a[4] / (float)(3 * f);
    float smooth = a[5] / (float)n;
    float normal = 1.0f - a[6] / (float)n;
    out[0] = chamfer + 2.0f * edge + smooth + 0.5f * normal;
  }
}

extern "C" void kernel_launch(void* const* d_in, const int* in_sizes, int n_in,
                              void* d_out, int out_size, void* d_ws, size_t ws_size,
                              hipStream_t stream) {
  const float* sv = (const float*)d_in[0];
  const float* sn = (const float*)d_in[1];
  const float* tv = (const float*)d_in[2];
  const float* tn = (const float*)d_in[3];
  const float* tp = (const float*)d_in[4];
  const float* gp = (const float*)d_in[5];
  const int*   fc = (const int*)d_in[6];
  const int n = in_sizes[0] / 3;
  const int m = in_sizes[2] / 3;
  const int p = in_sizes[4] / 3;
  const int g = in_sizes[5] / 3;
  const int f = in_sizes[6] / 3;

  // ws layout
  char* w = (char*)d_ws;
  unsigned long long* min64 = (unsigned long long*)w; w += (size_t)n * 8;
  unsigned* minbase = (unsigned*)w; w += (size_t)(n + p + n + g) * 4;
  float* nbr = (float*)w; w += (size_t)n * 3 * 4;   // zero region starts here
  float* deg = (float*)w; w += (size_t)n * 4;
  float* acc = (float*)w; w += 8 * 4;
  int* cnt = (int*)w;

  unsigned* minA_tp = minbase;
  unsigned* minB_tp = minA_tp + n;
  unsigned* minA_gt = minB_tp + p;
  unsigned* minB_gt = minA_gt + n;

  const int nmin = n + p + n + g;
  const int nz = n * 3 + n + 8 + 1;   // nbr, deg, acc, cnt

  init_ws_kernel<<<64, BLK, 0, stream>>>(min64, n, minbase, nmin, nbr, nz);

  Desc d;
  d.A[0] = sv; d.B[0] = tp; d.out[0] = minA_tp;
  d.A[1] = tp; d.B[1] = sv; d.out[1] = minB_tp;
  d.A[2] = sv; d.B[2] = gp; d.out[2] = minA_gt;
  d.A[3] = gp; d.B[3] = sv; d.out[3] = minB_gt;
  d.A[4] = sv; d.B[4] = tv; d.out[4] = min64;
  d.fc = fc; d.f = f; d.sv = sv;
  d.nbr = nbr; d.deg = deg; d.acc = acc;
  d.nRows = n; d.nCols = n;  // all passes 8192x8192

  // Grid: 4 x 64 x 6 = 1536 blocks (~6 blocks/CU, 24 waves/CU)
  dim3 pgrid((n + TA * BLK - 1) / (TA * BLK), (n + JC - 1) / JC, 6);
  mega_kernel<<<pgrid, BLK, 0, stream>>>(d);

  dim3 tgrid((n + BLK - 1) / BLK, 6);
  post_kernel<<<tgrid, BLK, 0, stream>>>(sv, sn, tn, tp, gp, nbr, deg,
                                         minbase, min64, n, p, g, f,
                                         acc, cnt, (float*)d_out);
}